// Round 10
// baseline (29.409 us; speedup 1.0000x reference)
//
#include <hip/hip_runtime.h>
#include <math.h>

#define EPSF 1e-20f
#define NEG_INF (-INFINITY)

__device__ __forceinline__ float softplusf(float x) {
    return fmaxf(x, 0.0f) + log1pf(expf(-fabsf(x)));
}
// fast reciprocal (v_rcp_f32) — ONLY for tolerance-protected epilogue math,
// never for argmax comparison values.
__device__ __forceinline__ float fastrcp(float x) {
    return __builtin_amdgcn_rcpf(x);
}

// Stage-B run: one input row, 6 consecutive windows (wn = 6s .. 6s+5),
// 14 elements (cols cb..cb+13), covered by de/ce[OFF..OFF+13] loaded from
// 4 aligned float4s at drow+align (align = cb-OFF). Each element's product
// and EXACT quotient computed ONCE; pairs (j=2p,2p+1) then windows
// (pairs t,t+1) combined with strict > in ascending-j order — identical
// tie-break to the reference's flat argmax. Static masks via JLO/JHI.
template<int OFF, int JLO, int JHI>
__device__ __forceinline__ void stageB_run(
    const float* __restrict__ drow, const float* __restrict__ crow,
    int align, bool rv, int wr, int s,
    float4 (*W4)[35], float (*W1)[35])
{
    const float4* dq = (const float4*)(drow + align);
    const float4* cq = (const float4*)(crow + align);
    float4 dqa = dq[0], dqb = dq[1], dqc = dq[2], dqd = dq[3];
    float4 cqa = cq[0], cqb = cq[1], cqc = cq[2], cqd = cq[3];
    float de[16] = { dqa.x,dqa.y,dqa.z,dqa.w, dqb.x,dqb.y,dqb.z,dqb.w,
                     dqc.x,dqc.y,dqc.z,dqc.w, dqd.x,dqd.y,dqd.z,dqd.w };
    float ce[16] = { cqa.x,cqa.y,cqa.z,cqa.w, cqb.x,cqb.y,cqb.z,cqb.w,
                     cqc.x,cqc.y,cqc.z,cqc.w, cqd.x,cqd.y,cqd.z,cqd.w };

    // pairs p = 0..6 over local elements j = 2p, 2p+1
    float pd1[7], pc1[7], pb2[7], pd2[7], pc2[7];
    #pragma unroll
    for (int p = 0; p < 7; ++p) {
        float w1d = NEG_INF, w1c = 1.0f;          // recomputed v1 = -inf can't win
        float b1  = NEG_INF;
        float b2  = NEG_INF, w2d = 0.f, w2c = 0.f;
        #pragma unroll
        for (int e = 0; e < 2; ++e) {
            const int j = 2 * p + e;
            if (j < JLO || j > JHI) continue;      // static col mask
            const int li = OFF + j;                // compile-time reg index
            float dv = de[li], cv = ce[li];
            float v1 = rv ? dv * cv          : NEG_INF;
            float v2 = rv ? cv / (dv + EPSF) : NEG_INF;   // EXACT div, once/element
            bool t1 = v1 > b1;
            b1 = t1 ? v1 : b1; w1d = t1 ? dv : w1d; w1c = t1 ? cv : w1c;
            bool t2 = v2 > b2;
            b2 = t2 ? v2 : b2; w2d = t2 ? dv : w2d; w2c = t2 ? cv : w2c;
        }
        pd1[p] = w1d; pc1[p] = w1c; pb2[p] = b2; pd2[p] = w2d; pc2[p] = w2c;
    }

    // windows t = 0..5 -> wn = 6s+t, combining pairs t, t+1 (ascending j)
    #pragma unroll
    for (int t = 0; t < 6; ++t) {
        int wn = 6 * s + t;
        if (wn < 34) {
            float b1  = pd1[t] * pc1[t];           // bit-exact recompute
            float w1d = pd1[t], w1c = pc1[t];
            float v1n = pd1[t + 1] * pc1[t + 1];
            bool t1 = v1n > b1;
            w1d = t1 ? pd1[t + 1] : w1d; w1c = t1 ? pc1[t + 1] : w1c;
            float b2  = pb2[t];
            float w2d = pd2[t], w2c = pc2[t];
            bool t2 = pb2[t + 1] > b2;
            b2 = t2 ? pb2[t + 1] : b2; w2d = t2 ? pd2[t + 1] : w2d; w2c = t2 ? pc2[t + 1] : w2c;
            W4[wr][wn] = make_float4(w1d, w1c, b2, w2d);
            W1[wr][wn] = w2c;
        }
    }
}

// One block = 32x64 output tile of one (b,c) plane. 2048 blocks x 256 threads.
// Stage B: per-row RUN units (38 rows x 6 segs = 228), each = 6 windows,
//          8 float4 loads, 14 exact divides (vs 36 loads / 24 divides).
// Stage C: vertical 4-row combine (flat-order strict >) + propagation -> lx.
// Stage D: 4-tap transposed depthwise conv + fused epilogue.
__global__ __launch_bounds__(256, 4) void fused_sndeconv(
    const float* __restrict__ d, const float* __restrict__ cd,
    const float* __restrict__ s, const float* __restrict__ cs,
    const float* __restrict__ w_s_from_d, const float* __restrict__ w_prop,
    const float* __restrict__ spatial_weight, const float* __restrict__ bias,
    float* __restrict__ s_out, float* __restrict__ cs_out)
{
    __shared__ float4 W4[38][35];        // (d1, c1, v2, d2)  21.3 KB (35: bank spread)
    __shared__ float  W1[38][35];        // (c2)               5.3 KB
    __shared__ float  lx1[18][36];       //  2.6 KB
    __shared__ float  lx2[18][36];       //  2.6 KB
    __shared__ float  sws[16];

    const int tid = threadIdx.x;
    const int blk = blockIdx.x;
    const int bc  = blk >> 5;            // plane 0..63
    const int tl  = blk & 31;
    const int by  = tl >> 2;             // 0..7  (32-row bands)
    const int bx  = tl & 3;              // 0..3  (64-col bands)
    const int c   = bc & 15;

    const int ib = by << 5;              // output row base
    const int jb = bx << 6;              // output col base
    const int mB = (ib >> 1) - 1;        // x-row base (18 rows)
    const int nB = (jb >> 1) - 1;        // x-col base (34 cols)
    const int rB = 2 * mB - 1;           // input row base (38 rows)
    const int cB = 2 * nB - 1;           // input col base (= 64*bx - 3, ≡1 mod 4)

    if (tid < 16) sws[tid] = softplusf(spatial_weight[c * 16 + tid]);

    const float* dp  = d  + (size_t)bc * 65536;
    const float* cdp = cd + (size_t)bc * 65536;
    const float* sp  = s  + (size_t)bc * 16384;
    const float* csp = cs + (size_t)bc * 16384;

    const float a0 = w_s_from_d[0];
    const float a1 = w_s_from_d[1];
    const float wp = softplusf(w_prop[0]);
    const float rwp1 = fastrcp(wp + 1.0f);

    // ---------------- stage B: run units (s-major: edge segs cluster in waves) ----
    if (tid < 228) {
        int sgi = tid / 38;              // segment 0..5
        int wr  = tid - sgi * 38;        // row 0..37
        int r   = rB + wr;
        int rl  = r < 0 ? 0 : (r > 255 ? 255 : r);
        bool rv = (r >= 0) && (r < 256);
        int cb  = cB + 12 * sgi;         // first window's first col (odd, ≡1 mod 4)
        int align = cb - 1;
        align = align < 0 ? 0 : (align > 240 ? 240 : align);
        const float* drow = dp  + rl * 256;
        const float* crow = cdp + rl * 256;

        bool eL = (bx == 0) && (sgi == 0);   // cb = -3  -> OFF = cb - align = -3
        bool eR = (bx == 3) && (sgi == 5);   // cb = 249 -> align 240, OFF = 9
        if (eL)      stageB_run<-3, 3, 13>(drow, crow, align, rv, wr, sgi, W4, W1);
        else if (eR) stageB_run< 9, 0,  6>(drow, crow, align, rv, wr, sgi, W4, W1);
        else         stageB_run< 1, 0, 13>(drow, crow, align, rv, wr, sgi, W4, W1);
    }
    __syncthreads();

    // ---------------- stage C: vertical combine + prop math ----------------
    #pragma unroll
    for (int it = 0; it < 3; ++it) {
        int unit = tid + 256 * it;
        if (unit < 612) {
            int cmr = unit / 34;
            int cn  = unit - cmr * 34;
            int m   = mB + cmr;
            int n   = nB + cn;
            if (m < 0 || m > 127 || n < 0 || n > 127) {
                lx1[cmr][cn] = 0.f;
                lx2[cmr][cn] = 0.f;
            } else {
                // issue global loads FIRST (overlap with LDS combine below)
                float sv   = sp[m * 128 + n];
                float csv  = csp[m * 128 + n];

                float4 a4 = W4[2 * cmr + 0][cn];
                float  e1 = W1[2 * cmr + 0][cn];
                float d1 = a4.x, c1 = a4.y, b2 = a4.z, d2 = a4.w, c2 = e1;
                float b1 = d1 * c1;                  // recomputed v1 (bit-exact)
                #pragma unroll
                for (int k = 1; k < 4; ++k) {
                    float4 w4 = W4[2 * cmr + k][cn];
                    float  w1 = W1[2 * cmr + k][cn];
                    float v1 = w4.x * w4.y;
                    bool t1 = v1 > b1;
                    b1 = t1 ? v1 : b1; d1 = t1 ? w4.x : d1; c1 = t1 ? w4.y : c1;
                    bool t2 = w4.z > b2;
                    b2 = t2 ? w4.z : b2; d2 = t2 ? w4.w : d2; c2 = t2 ? w1 : c2;
                }

                float mm_  = fabsf(d2 * fastrcp(d1 + EPSF));
                float sfd  = (1.0f - a0 - a1) * mm_ + a0 * mm_ * mm_ + a1 * mm_ * mm_ * mm_;
                float csfd = c1 * c2;
                float den  = wp * csv + csfd;
                float spv  = (wp * csv * sv + csfd * sfd) * fastrcp(den + EPSF);
                float cp   = den * rwp1;
                lx1[cmr][cn] = cp * spv;
                lx2[cmr][cn] = cp;
            }
        }
    }
    __syncthreads();

    // ---------------- stage D: deconv + epilogue (8 outputs/thread) ----------------
    int ii = tid >> 3, jq = tid & 7;
    int i  = ib + ii;
    int u0 = (i + 1) & 1;
    int m0 = (i + 1 - u0) >> 1;
    int pr0 = m0 - mB;                    // 1..17
    int pr1 = pr0 - 1;                    // 0..16
    float rv0 = (m0 <= 127) ? 1.f : 0.f;
    float rv1 = (m0 >= 1)   ? 1.f : 0.f;

    float wA0 = sws[u0*4 + 0], wA1 = sws[u0*4 + 1], wA2 = sws[u0*4 + 2], wA3 = sws[u0*4 + 3];
    float wC0 = sws[(u0+2)*4 + 0], wC1 = sws[(u0+2)*4 + 1], wC2 = sws[(u0+2)*4 + 2], wC3 = sws[(u0+2)*4 + 3];
    float bv  = bias[c];

    int bb = 4 * jq;
    float r1a[6], r1b[6], r2a[6], r2b[6];
    {
        const float* p = &lx1[pr0][bb];
        float4 t4 = *(const float4*)p;  float2 t2 = *(const float2*)(p + 4);
        r1a[0]=t4.x; r1a[1]=t4.y; r1a[2]=t4.z; r1a[3]=t4.w; r1a[4]=t2.x; r1a[5]=t2.y;
    }
    {
        const float* p = &lx1[pr1][bb];
        float4 t4 = *(const float4*)p;  float2 t2 = *(const float2*)(p + 4);
        r1b[0]=t4.x; r1b[1]=t4.y; r1b[2]=t4.z; r1b[3]=t4.w; r1b[4]=t2.x; r1b[5]=t2.y;
    }
    {
        const float* p = &lx2[pr0][bb];
        float4 t4 = *(const float4*)p;  float2 t2 = *(const float2*)(p + 4);
        r2a[0]=t4.x; r2a[1]=t4.y; r2a[2]=t4.z; r2a[3]=t4.w; r2a[4]=t2.x; r2a[5]=t2.y;
    }
    {
        const float* p = &lx2[pr1][bb];
        float4 t4 = *(const float4*)p;  float2 t2 = *(const float2*)(p + 4);
        r2b[0]=t4.x; r2b[1]=t4.y; r2b[2]=t4.z; r2b[3]=t4.w; r2b[4]=t2.x; r2b[5]=t2.y;
    }

    int n0b = (jb >> 1) + 4 * jq;
    size_t orow = (size_t)bc * 65536 + (size_t)i * 256 + jb + 8 * jq;

    float so[4], co[4];
    #pragma unroll
    for (int e = 0; e < 8; ++e) {
        const int v0 = (e + 1) & 1;
        const int hi = 1 + ((e + 1) >> 1);
        const int lo = hi - 1;
        float swa = v0 ? wA1 : wA0;       // (u0,   v0)
        float swb = v0 ? wA3 : wA2;       // (u0,   v0+2)
        float swc = v0 ? wC1 : wC0;       // (u0+2, v0)
        float swd = v0 ? wC3 : wC2;       // (u0+2, v0+2)

        float nom = swa*r1a[hi] + swb*r1a[lo] + swc*r1b[hi] + swd*r1b[lo];
        float den = swa*r2a[hi] + swb*r2a[lo] + swc*r2b[hi] + swd*r2b[lo];

        int n0 = n0b + ((e + 1) >> 1);
        float nvh = (n0 <= 127) ? 1.f : 0.f;
        float nvl = (n0 >= 1)   ? 1.f : 0.f;
        float cden = rv0 * (swa*nvh + swb*nvl) + rv1 * (swc*nvh + swd*nvl);

        so[e & 3] = nom * fastrcp(den + EPSF) + bv;
        co[e & 3] = den * fastrcp(cden);
        if ((e & 3) == 3) {
            *(float4*)(s_out  + orow + (e - 3)) = make_float4(so[0], so[1], so[2], so[3]);
            *(float4*)(cs_out + orow + (e - 3)) = make_float4(co[0], co[1], co[2], co[3]);
        }
    }
}

extern "C" void kernel_launch(void* const* d_in, const int* in_sizes, int n_in,
                              void* d_out, int out_size, void* d_ws, size_t ws_size,
                              hipStream_t stream) {
    const float* d    = (const float*)d_in[0];
    const float* cd   = (const float*)d_in[1];
    const float* s    = (const float*)d_in[2];
    const float* cs   = (const float*)d_in[3];
    const float* wsd  = (const float*)d_in[4];
    const float* wpr  = (const float*)d_in[5];
    const float* spw  = (const float*)d_in[6];
    const float* bias = (const float*)d_in[7];

    float* out  = (float*)d_out;
    float* s_o  = out;
    float* cs_o = out + (size_t)4 * 16 * 256 * 256;

    // 64 planes x 32 tiles (8x4 of 32x64 outputs) = 2048 blocks
    fused_sndeconv<<<2048, 256, 0, stream>>>(d, cd, s, cs, wsd, wpr, spw, bias, s_o, cs_o);
}

// Round 11
// 23.922 us; speedup vs baseline: 1.2293x; 1.2293x over previous
//
#include <hip/hip_runtime.h>
#include <math.h>

#define EPSF 1e-20f
#define NEG_INF (-INFINITY)

__device__ __forceinline__ float softplusf(float x) {
    return fmaxf(x, 0.0f) + log1pf(expf(-fabsf(x)));
}
// fast reciprocal (v_rcp_f32) — ONLY for tolerance-protected epilogue math,
// never for argmax comparison values.
__device__ __forceinline__ float fastrcp(float x) {
    return __builtin_amdgcn_rcpf(x);
}

// Issue the 4 global loads for stage-B pair unit `unit` (pre-clamped to
// [0,1329]). Pure loads — no dependent compute, so they pipeline.
__device__ __forceinline__ void issue_pair_loads(
    int unit, const float* __restrict__ dp, const float* __restrict__ cdp,
    int rB, int cB,
    float& d0, float& d1, float& c0, float& c1)
{
    int wr = unit / 35;
    int t  = unit - wr * 35;
    int r  = rB + wr;
    int rl = r < 0 ? 0 : (r > 255 ? 255 : r);
    int col0 = cB + 2 * t;                       // odd
    int c0i = col0 < 0 ? 0 : (col0 > 255 ? 255 : col0);
    int c1i = col0 + 1 < 0 ? 0 : (col0 + 1 > 255 ? 255 : col0 + 1);
    const float* drow = dp  + rl * 256;
    const float* crow = cdp + rl * 256;
    d0 = drow[c0i];
    d1 = drow[c1i];
    c0 = crow[c0i];
    c1 = crow[c1i];
}

// One block = 32x64 output tile of one (b,c) plane. 2048 blocks x 256 threads.
// Stage B: PAIR-granularity dual argmax (38 rows x 35 col-pairs = 1330 units),
//          2-deep software-pipelined. Each element's product and EXACT
//          quotient computed ONCE (2660 divides/block vs round-9's 5168;
//          5320 loads vs 7752). Payload 20B: W4=(d1,c1,v2,d2), W1=(c2);
//          chain-1 value recomputed as d1*c1 in stage C (bit-exact).
// Stage C: window = pairs (cn, cn+1) x 4 rows, combined in kh-major /
//          kw-ascending order with strict > == reference flat argmax.
// Stage D: 4-tap transposed depthwise conv + fused epilogue.
// Grid swizzled XCD-chunked (2048 % 8 == 0 -> bijective) so vertically-
// overlapping tiles share an XCD L2.
__global__ __launch_bounds__(256, 4) void fused_sndeconv(
    const float* __restrict__ d, const float* __restrict__ cd,
    const float* __restrict__ s, const float* __restrict__ cs,
    const float* __restrict__ w_s_from_d, const float* __restrict__ w_prop,
    const float* __restrict__ spatial_weight, const float* __restrict__ bias,
    float* __restrict__ s_out, float* __restrict__ cs_out)
{
    __shared__ float4 W4[38][35];        // (d1, c1, v2, d2)  20.8 KB
    __shared__ float  W1[38][35];        // (c2)               5.2 KB
    __shared__ float  lx1[18][36];       //  2.6 KB
    __shared__ float  lx2[18][36];       //  2.6 KB
    __shared__ float  sws[16];           // total 31.2 KB -> 5 blocks/CU

    const int tid = threadIdx.x;
    // XCD-chunked swizzle: XCD(bid)=bid%8 processes one contiguous 256-block
    // chunk -> vertical neighbors (blk±4) co-resident on the same L2.
    const int bid = blockIdx.x;
    const int blk = (bid & 7) * 256 + (bid >> 3);
    const int bc  = blk >> 5;            // plane 0..63
    const int tl  = blk & 31;
    const int by  = tl >> 2;             // 0..7  (32-row bands)
    const int bx  = tl & 3;              // 0..3  (64-col bands)
    const int c   = bc & 15;

    const int ib = by << 5;              // output row base
    const int jb = bx << 6;              // output col base
    const int mB = (ib >> 1) - 1;        // x-row base (18 rows)
    const int nB = (jb >> 1) - 1;        // x-col base (34 cols)
    const int rB = 2 * mB - 1;           // input row base (38 rows)
    const int cB = 2 * nB - 1;           // input col base (odd); pair t = cols cB+2t, cB+2t+1

    if (tid < 16) sws[tid] = softplusf(spatial_weight[c * 16 + tid]);

    const float* dp  = d  + (size_t)bc * 65536;
    const float* cdp = cd + (size_t)bc * 65536;
    const float* sp  = s  + (size_t)bc * 16384;
    const float* csp = cs + (size_t)bc * 16384;

    const float a0 = w_s_from_d[0];
    const float a1 = w_s_from_d[1];
    const float wp = softplusf(w_prop[0]);
    const float rwp1 = fastrcp(wp + 1.0f);

    // ---------------- stage B: pipelined pair-granularity argmax ----------------
    {
        float pd0[2], pd1[2], pc0[2], pc1[2];

        // prologue: unit for it=0 (tid < 256 < 1330, no clamp needed)
        issue_pair_loads(tid, dp, cdp, rB, cB, pd0[0], pd1[0], pc0[0], pc1[0]);

        #pragma unroll
        for (int it = 0; it < 6; ++it) {
            const int cur = it & 1;
            const int nxt = cur ^ 1;
            if (it < 5) {                        // compile-time after unroll
                int nu = tid + 256 * (it + 1);
                nu = nu < 1330 ? nu : 1329;      // clamp: safe redundant loads
                issue_pair_loads(nu, dp, cdp, rB, cB,
                                 pd0[nxt], pd1[nxt], pc0[nxt], pc1[nxt]);
            }
            int unit = tid + 256 * it;
            if (unit < 1330) {
                int wr = unit / 35;
                int t  = unit - wr * 35;
                int r  = rB + wr;
                int col0 = cB + 2 * t;           // odd
                bool rv  = (r >= 0) && (r < 256);
                bool mv0 = rv && (col0 >= 0) && (col0 <= 255);
                bool mv1 = rv && (col0 >= -1) && (col0 <= 254);

                float dv0 = pd0[cur], dv1 = pd1[cur];
                float cv0 = pc0[cur], cv1 = pc1[cur];

                // chain1 payload init: (-inf, 1) so recomputed v1 = -inf can't win
                float b1 = NEG_INF, w1d = NEG_INF, w1c = 1.0f;
                float b2 = NEG_INF, w2d = 0.f,     w2c = 0.f;

                // element kw-even (local e=0)
                float v1 = mv0 ? dv0 * cv0          : NEG_INF;
                float v2 = mv0 ? cv0 / (dv0 + EPSF) : NEG_INF;  // EXACT div
                bool t1 = v1 > b1;
                b1 = t1 ? v1 : b1; w1d = t1 ? dv0 : w1d; w1c = t1 ? cv0 : w1c;
                bool t2 = v2 > b2;
                b2 = t2 ? v2 : b2; w2d = t2 ? dv0 : w2d; w2c = t2 ? cv0 : w2c;
                // element kw-odd (local e=1)
                v1 = mv1 ? dv1 * cv1          : NEG_INF;
                v2 = mv1 ? cv1 / (dv1 + EPSF) : NEG_INF;        // EXACT div
                t1 = v1 > b1;
                b1 = t1 ? v1 : b1; w1d = t1 ? dv1 : w1d; w1c = t1 ? cv1 : w1c;
                t2 = v2 > b2;
                b2 = t2 ? v2 : b2; w2d = t2 ? dv1 : w2d; w2c = t2 ? cv1 : w2c;

                W4[wr][t] = make_float4(w1d, w1c, b2, w2d);
                W1[wr][t] = w2c;
            }
        }
    }
    __syncthreads();

    // ---------------- stage C: 2-pair x 4-row combine + prop math ----------------
    #pragma unroll
    for (int it = 0; it < 3; ++it) {
        int unit = tid + 256 * it;
        if (unit < 612) {
            int cmr = unit / 34;
            int cn  = unit - cmr * 34;
            int m   = mB + cmr;
            int n   = nB + cn;
            if (m < 0 || m > 127 || n < 0 || n > 127) {
                lx1[cmr][cn] = 0.f;
                lx2[cmr][cn] = 0.f;
            } else {
                // issue global loads FIRST (overlap with LDS combine below)
                float sv   = sp[m * 128 + n];
                float csv  = csp[m * 128 + n];

                float b1 = NEG_INF, d1 = NEG_INF, c1 = 1.0f;
                float b2 = NEG_INF, d2 = 0.f,     c2 = 0.f;
                // kh-major, kw-ascending: row k, pair cn (kw 0,1) then cn+1 (kw 2,3)
                #pragma unroll
                for (int k = 0; k < 4; ++k) {
                    int row = 2 * cmr + k;
                    #pragma unroll
                    for (int dt = 0; dt < 2; ++dt) {
                        float4 w4 = W4[row][cn + dt];
                        float  w1 = W1[row][cn + dt];
                        float v1 = w4.x * w4.y;          // bit-exact recompute
                        bool t1 = v1 > b1;
                        b1 = t1 ? v1 : b1; d1 = t1 ? w4.x : d1; c1 = t1 ? w4.y : c1;
                        bool t2 = w4.z > b2;
                        b2 = t2 ? w4.z : b2; d2 = t2 ? w4.w : d2; c2 = t2 ? w1 : c2;
                    }
                }

                float mm_  = fabsf(d2 * fastrcp(d1 + EPSF));
                float sfd  = (1.0f - a0 - a1) * mm_ + a0 * mm_ * mm_ + a1 * mm_ * mm_ * mm_;
                float csfd = c1 * c2;
                float den  = wp * csv + csfd;
                float spv  = (wp * csv * sv + csfd * sfd) * fastrcp(den + EPSF);
                float cp   = den * rwp1;
                lx1[cmr][cn] = cp * spv;
                lx2[cmr][cn] = cp;
            }
        }
    }
    __syncthreads();

    // ---------------- stage D: deconv + epilogue (8 outputs/thread) ----------------
    int ii = tid >> 3, jq = tid & 7;
    int i  = ib + ii;
    int u0 = (i + 1) & 1;
    int m0 = (i + 1 - u0) >> 1;
    int pr0 = m0 - mB;                    // 1..17
    int pr1 = pr0 - 1;                    // 0..16
    float rv0 = (m0 <= 127) ? 1.f : 0.f;
    float rv1 = (m0 >= 1)   ? 1.f : 0.f;

    float wA0 = sws[u0*4 + 0], wA1 = sws[u0*4 + 1], wA2 = sws[u0*4 + 2], wA3 = sws[u0*4 + 3];
    float wC0 = sws[(u0+2)*4 + 0], wC1 = sws[(u0+2)*4 + 1], wC2 = sws[(u0+2)*4 + 2], wC3 = sws[(u0+2)*4 + 3];
    float bv  = bias[c];

    int bb = 4 * jq;
    float r1a[6], r1b[6], r2a[6], r2b[6];
    {
        const float* p = &lx1[pr0][bb];
        float4 t4 = *(const float4*)p;  float2 t2 = *(const float2*)(p + 4);
        r1a[0]=t4.x; r1a[1]=t4.y; r1a[2]=t4.z; r1a[3]=t4.w; r1a[4]=t2.x; r1a[5]=t2.y;
    }
    {
        const float* p = &lx1[pr1][bb];
        float4 t4 = *(const float4*)p;  float2 t2 = *(const float2*)(p + 4);
        r1b[0]=t4.x; r1b[1]=t4.y; r1b[2]=t4.z; r1b[3]=t4.w; r1b[4]=t2.x; r1b[5]=t2.y;
    }
    {
        const float* p = &lx2[pr0][bb];
        float4 t4 = *(const float4*)p;  float2 t2 = *(const float2*)(p + 4);
        r2a[0]=t4.x; r2a[1]=t4.y; r2a[2]=t4.z; r2a[3]=t4.w; r2a[4]=t2.x; r2a[5]=t2.y;
    }
    {
        const float* p = &lx2[pr1][bb];
        float4 t4 = *(const float4*)p;  float2 t2 = *(const float2*)(p + 4);
        r2b[0]=t4.x; r2b[1]=t4.y; r2b[2]=t4.z; r2b[3]=t4.w; r2b[4]=t2.x; r2b[5]=t2.y;
    }

    int n0b = (jb >> 1) + 4 * jq;
    size_t orow = (size_t)bc * 65536 + (size_t)i * 256 + jb + 8 * jq;

    float so[4], co[4];
    #pragma unroll
    for (int e = 0; e < 8; ++e) {
        const int v0 = (e + 1) & 1;
        const int hi = 1 + ((e + 1) >> 1);
        const int lo = hi - 1;
        float swa = v0 ? wA1 : wA0;       // (u0,   v0)
        float swb = v0 ? wA3 : wA2;       // (u0,   v0+2)
        float swc = v0 ? wC1 : wC0;       // (u0+2, v0)
        float swd = v0 ? wC3 : wC2;       // (u0+2, v0+2)

        float nom = swa*r1a[hi] + swb*r1a[lo] + swc*r1b[hi] + swd*r1b[lo];
        float den = swa*r2a[hi] + swb*r2a[lo] + swc*r2b[hi] + swd*r2b[lo];

        int n0 = n0b + ((e + 1) >> 1);
        float nvh = (n0 <= 127) ? 1.f : 0.f;
        float nvl = (n0 >= 1)   ? 1.f : 0.f;
        float cden = rv0 * (swa*nvh + swb*nvl) + rv1 * (swc*nvh + swd*nvl);

        so[e & 3] = nom * fastrcp(den + EPSF) + bv;
        co[e & 3] = den * fastrcp(cden);
        if ((e & 3) == 3) {
            *(float4*)(s_out  + orow + (e - 3)) = make_float4(so[0], so[1], so[2], so[3]);
            *(float4*)(cs_out + orow + (e - 3)) = make_float4(co[0], co[1], co[2], co[3]);
        }
    }
}

extern "C" void kernel_launch(void* const* d_in, const int* in_sizes, int n_in,
                              void* d_out, int out_size, void* d_ws, size_t ws_size,
                              hipStream_t stream) {
    const float* d    = (const float*)d_in[0];
    const float* cd   = (const float*)d_in[1];
    const float* s    = (const float*)d_in[2];
    const float* cs   = (const float*)d_in[3];
    const float* wsd  = (const float*)d_in[4];
    const float* wpr  = (const float*)d_in[5];
    const float* spw  = (const float*)d_in[6];
    const float* bias = (const float*)d_in[7];

    float* out  = (float*)d_out;
    float* s_o  = out;
    float* cs_o = out + (size_t)4 * 16 * 256 * 256;

    // 64 planes x 32 tiles (8x4 of 32x64 outputs) = 2048 blocks
    fused_sndeconv<<<2048, 256, 0, stream>>>(d, cd, s, cs, wsd, wpr, spw, bias, s_o, cs_o);
}

// Round 12
// 23.832 us; speedup vs baseline: 1.2340x; 1.0038x over previous
//
#include <hip/hip_runtime.h>
#include <math.h>

#define EPSF 1e-20f
#define NEG_INF (-INFINITY)

struct TrueT  { static constexpr bool value = true;  };
struct FalseT { static constexpr bool value = false; };

__device__ __forceinline__ float softplusf(float x) {
    return fmaxf(x, 0.0f) + log1pf(expf(-fabsf(x)));
}
// fast reciprocal (v_rcp_f32) — ONLY for tolerance-protected epilogue math,
// never for argmax comparison values.
__device__ __forceinline__ float fastrcp(float x) {
    return __builtin_amdgcn_rcpf(x);
}

// Issue the 4 global loads for stage-B pair unit `unit` (pre-clamped to
// [0,1329]). Pure loads — no dependent compute, so they pipeline.
// INTERIOR: all row/col clamps fold away (tile proven in-bounds).
template<bool INTERIOR>
__device__ __forceinline__ void issue_pair_loads(
    int unit, const float* __restrict__ dp, const float* __restrict__ cdp,
    int rB, int cB,
    float& d0, float& d1, float& c0, float& c1)
{
    int wr = unit / 35;
    int t  = unit - wr * 35;
    int r  = rB + wr;
    int rl = INTERIOR ? r : (r < 0 ? 0 : (r > 255 ? 255 : r));
    int col0 = cB + 2 * t;                       // odd
    int c0i, c1i;
    if (INTERIOR) { c0i = col0; c1i = col0 + 1; }
    else {
        c0i = col0 < 0 ? 0 : (col0 > 255 ? 255 : col0);
        c1i = col0 + 1 < 0 ? 0 : (col0 + 1 > 255 ? 255 : col0 + 1);
    }
    const float* drow = dp  + rl * 256;
    const float* crow = cdp + rl * 256;
    d0 = drow[c0i];
    d1 = drow[c1i];
    c0 = crow[c0i];
    c1 = crow[c1i];
}

// One block = 32x64 output tile of one (b,c) plane. 2048 blocks x 256 threads.
// Stage B: PAIR-granularity dual argmax (38 rows x 35 col-pairs = 1330 units),
//          3-deep software-pipelined; each element's product and EXACT
//          quotient computed once. Payload 20B: W4=(d1,c1,v2,d2), W1=(c2);
//          chain-1 value recomputed as d1*c1 downstream (bit-exact).
// Stage C: window = pairs (cn,cn+1) x 4 rows, kh-major/kw-ascending strict >
//          == reference flat argmax; s/cs values PREFETCHED before stage B.
// Stage D: 4-tap transposed depthwise conv + fused epilogue.
// Interior tiles (by 1..6, bx 1..2) take a mask-free specialization.
__global__ __launch_bounds__(256, 4) void fused_sndeconv(
    const float* __restrict__ d, const float* __restrict__ cd,
    const float* __restrict__ s, const float* __restrict__ cs,
    const float* __restrict__ w_s_from_d, const float* __restrict__ w_prop,
    const float* __restrict__ spatial_weight, const float* __restrict__ bias,
    float* __restrict__ s_out, float* __restrict__ cs_out)
{
    __shared__ float4 W4[38][35];        // (d1, c1, v2, d2)  20.8 KB
    __shared__ float  W1[38][35];        // (c2)               5.2 KB
    __shared__ float  lx1[18][36];       //  2.6 KB
    __shared__ float  lx2[18][36];       //  2.6 KB
    __shared__ float  sws[16];           // total ~31.3 KB -> 5 blocks/CU

    const int tid = threadIdx.x;
    // XCD-chunked swizzle (2048 % 8 == 0 -> bijective): vertical neighbor
    // tiles co-resident on one XCD L2.
    const int bid = blockIdx.x;
    const int blk = (bid & 7) * 256 + (bid >> 3);
    const int bc  = blk >> 5;            // plane 0..63
    const int tl  = blk & 31;
    const int by  = tl >> 2;             // 0..7  (32-row bands)
    const int bx  = tl & 3;              // 0..3  (64-col bands)
    const int c   = bc & 15;

    const int ib = by << 5;              // output row base
    const int jb = bx << 6;              // output col base
    const int mB = (ib >> 1) - 1;        // x-row base (18 rows)
    const int nB = (jb >> 1) - 1;        // x-col base (34 cols)
    const int rB = 2 * mB - 1;           // input row base (38 rows)
    const int cB = 2 * nB - 1;           // input col base (odd)

    if (tid < 16) sws[tid] = softplusf(spatial_weight[c * 16 + tid]);

    const float* dp  = d  + (size_t)bc * 65536;
    const float* cdp = cd + (size_t)bc * 65536;
    const float* sp  = s  + (size_t)bc * 16384;
    const float* csp = cs + (size_t)bc * 16384;

    const float a0 = w_s_from_d[0];
    const float a1 = w_s_from_d[1];
    const float wp = softplusf(w_prop[0]);
    const float rwp1 = fastrcp(wp + 1.0f);

    const bool interior = (by >= 1) && (by <= 6) && (bx >= 1) && (bx <= 2);

    auto runBC = [&](auto tag) {
        constexpr bool INT = decltype(tag)::value;

        // ---------- stage B: 3-deep pipelined pair argmax + C-prefetch ----------
        float pd0[3], pd1[3], pc0[3], pc1[3];
        float sv_pre[3], csv_pre[3];

        // prologue: units it=0,1 (tid+0, tid+256 < 1330, no clamp)
        issue_pair_loads<INT>(tid,       dp, cdp, rB, cB, pd0[0], pd1[0], pc0[0], pc1[0]);
        issue_pair_loads<INT>(tid + 256, dp, cdp, rB, cB, pd0[1], pd1[1], pc0[1], pc1[1]);

        // prefetch stage-C s/cs (6 loads ride under all of stage B)
        #pragma unroll
        for (int k = 0; k < 3; ++k) {
            int u = tid + 256 * k;
            u = u < 612 ? u : 611;               // clamp: redundant-safe
            int cmr = u / 34;
            int cn  = u - 34 * cmr;
            int m = mB + cmr;
            int n = nB + cn;
            if (!INT) {
                m = m < 0 ? 0 : (m > 127 ? 127 : m);
                n = n < 0 ? 0 : (n > 127 ? 127 : n);
            }
            sv_pre[k]  = sp [m * 128 + n];
            csv_pre[k] = csp[m * 128 + n];
        }

        #pragma unroll
        for (int it = 0; it < 6; ++it) {
            const int cur = it % 3;
            const int pre = (it + 2) % 3;
            if (it < 4) {                        // compile-time after unroll
                int nu = tid + 256 * (it + 2);
                nu = nu < 1330 ? nu : 1329;      // clamp: safe redundant loads
                issue_pair_loads<INT>(nu, dp, cdp, rB, cB,
                                      pd0[pre], pd1[pre], pc0[pre], pc1[pre]);
            }
            int unit = tid + 256 * it;
            if (unit < 1330) {
                int wr = unit / 35;
                int t  = unit - wr * 35;
                bool mv0, mv1;
                if (INT) { mv0 = true; mv1 = true; }
                else {
                    int r    = rB + wr;
                    int col0 = cB + 2 * t;       // odd
                    bool rv  = (r >= 0) && (r < 256);
                    mv0 = rv && (col0 >= 0)  && (col0 <= 255);
                    mv1 = rv && (col0 >= -1) && (col0 <= 254);
                }
                float dv0 = pd0[cur], dv1 = pd1[cur];
                float cv0 = pc0[cur], cv1 = pc1[cur];

                // chain1 payload init: (-inf, 1) so recomputed v1 = -inf can't win
                float b1 = NEG_INF, w1d = NEG_INF, w1c = 1.0f;
                float b2 = NEG_INF, w2d = 0.f,     w2c = 0.f;

                // element kw-even
                float v1 = mv0 ? dv0 * cv0          : NEG_INF;
                float v2 = mv0 ? cv0 / (dv0 + EPSF) : NEG_INF;  // EXACT div
                bool t1 = v1 > b1;
                b1 = t1 ? v1 : b1; w1d = t1 ? dv0 : w1d; w1c = t1 ? cv0 : w1c;
                bool t2 = v2 > b2;
                b2 = t2 ? v2 : b2; w2d = t2 ? dv0 : w2d; w2c = t2 ? cv0 : w2c;
                // element kw-odd
                v1 = mv1 ? dv1 * cv1          : NEG_INF;
                v2 = mv1 ? cv1 / (dv1 + EPSF) : NEG_INF;        // EXACT div
                t1 = v1 > b1;
                b1 = t1 ? v1 : b1; w1d = t1 ? dv1 : w1d; w1c = t1 ? cv1 : w1c;
                t2 = v2 > b2;
                b2 = t2 ? v2 : b2; w2d = t2 ? dv1 : w2d; w2c = t2 ? cv1 : w2c;

                W4[wr][t] = make_float4(w1d, w1c, b2, w2d);
                W1[wr][t] = w2c;
            }
        }
        __syncthreads();

        // ---------- stage C: 2-pair x 4-row combine + prop math ----------
        #pragma unroll
        for (int it = 0; it < 3; ++it) {
            int unit = tid + 256 * it;
            if (unit < 612) {
                int cmr = unit / 34;
                int cn  = unit - cmr * 34;
                int m   = mB + cmr;
                int n   = nB + cn;
                if (!INT && (m < 0 || m > 127 || n < 0 || n > 127)) {
                    lx1[cmr][cn] = 0.f;
                    lx2[cmr][cn] = 0.f;
                } else {
                    float sv  = sv_pre[it];
                    float csv = csv_pre[it];

                    float b1 = NEG_INF, d1 = NEG_INF, c1 = 1.0f;
                    float b2 = NEG_INF, d2 = 0.f,     c2 = 0.f;
                    // kh-major, kw-ascending: row k, pair cn then cn+1
                    #pragma unroll
                    for (int k = 0; k < 4; ++k) {
                        int row = 2 * cmr + k;
                        #pragma unroll
                        for (int dt = 0; dt < 2; ++dt) {
                            float4 w4 = W4[row][cn + dt];
                            float  w1 = W1[row][cn + dt];
                            float v1 = w4.x * w4.y;          // bit-exact recompute
                            bool t1 = v1 > b1;
                            b1 = t1 ? v1 : b1; d1 = t1 ? w4.x : d1; c1 = t1 ? w4.y : c1;
                            bool t2 = w4.z > b2;
                            b2 = t2 ? w4.z : b2; d2 = t2 ? w4.w : d2; c2 = t2 ? w1 : c2;
                        }
                    }

                    float mm_  = fabsf(d2 * fastrcp(d1 + EPSF));
                    float sfd  = (1.0f - a0 - a1) * mm_ + a0 * mm_ * mm_ + a1 * mm_ * mm_ * mm_;
                    float csfd = c1 * c2;
                    float den  = wp * csv + csfd;
                    float spv  = (wp * csv * sv + csfd * sfd) * fastrcp(den + EPSF);
                    float cp   = den * rwp1;
                    lx1[cmr][cn] = cp * spv;
                    lx2[cmr][cn] = cp;
                }
            }
        }
    };
    if (interior) runBC(TrueT{});
    else          runBC(FalseT{});
    __syncthreads();

    // ---------------- stage D: deconv + epilogue (8 outputs/thread) ----------------
    int ii = tid >> 3, jq = tid & 7;
    int i  = ib + ii;
    int u0 = (i + 1) & 1;
    int m0 = (i + 1 - u0) >> 1;
    int pr0 = m0 - mB;                    // 1..17
    int pr1 = pr0 - 1;                    // 0..16
    float rv0 = (m0 <= 127) ? 1.f : 0.f;
    float rv1 = (m0 >= 1)   ? 1.f : 0.f;

    float wA0 = sws[u0*4 + 0], wA1 = sws[u0*4 + 1], wA2 = sws[u0*4 + 2], wA3 = sws[u0*4 + 3];
    float wC0 = sws[(u0+2)*4 + 0], wC1 = sws[(u0+2)*4 + 1], wC2 = sws[(u0+2)*4 + 2], wC3 = sws[(u0+2)*4 + 3];
    float bv  = bias[c];

    int bb = 4 * jq;
    float r1a[6], r1b[6], r2a[6], r2b[6];
    {
        const float* p = &lx1[pr0][bb];
        float4 t4 = *(const float4*)p;  float2 t2 = *(const float2*)(p + 4);
        r1a[0]=t4.x; r1a[1]=t4.y; r1a[2]=t4.z; r1a[3]=t4.w; r1a[4]=t2.x; r1a[5]=t2.y;
    }
    {
        const float* p = &lx1[pr1][bb];
        float4 t4 = *(const float4*)p;  float2 t2 = *(const float2*)(p + 4);
        r1b[0]=t4.x; r1b[1]=t4.y; r1b[2]=t4.z; r1b[3]=t4.w; r1b[4]=t2.x; r1b[5]=t2.y;
    }
    {
        const float* p = &lx2[pr0][bb];
        float4 t4 = *(const float4*)p;  float2 t2 = *(const float2*)(p + 4);
        r2a[0]=t4.x; r2a[1]=t4.y; r2a[2]=t4.z; r2a[3]=t4.w; r2a[4]=t2.x; r2a[5]=t2.y;
    }
    {
        const float* p = &lx2[pr1][bb];
        float4 t4 = *(const float4*)p;  float2 t2 = *(const float2*)(p + 4);
        r2b[0]=t4.x; r2b[1]=t4.y; r2b[2]=t4.z; r2b[3]=t4.w; r2b[4]=t2.x; r2b[5]=t2.y;
    }

    int n0b = (jb >> 1) + 4 * jq;
    size_t orow = (size_t)bc * 65536 + (size_t)i * 256 + jb + 8 * jq;

    float so[4], co[4];
    #pragma unroll
    for (int e = 0; e < 8; ++e) {
        const int v0 = (e + 1) & 1;
        const int hi = 1 + ((e + 1) >> 1);
        const int lo = hi - 1;
        float swa = v0 ? wA1 : wA0;       // (u0,   v0)
        float swb = v0 ? wA3 : wA2;       // (u0,   v0+2)
        float swc = v0 ? wC1 : wC0;       // (u0+2, v0)
        float swd = v0 ? wC3 : wC2;       // (u0+2, v0+2)

        float nom = swa*r1a[hi] + swb*r1a[lo] + swc*r1b[hi] + swd*r1b[lo];
        float den = swa*r2a[hi] + swb*r2a[lo] + swc*r2b[hi] + swd*r2b[lo];

        int n0 = n0b + ((e + 1) >> 1);
        float nvh = (n0 <= 127) ? 1.f : 0.f;
        float nvl = (n0 >= 1)   ? 1.f : 0.f;
        float cden = rv0 * (swa*nvh + swb*nvl) + rv1 * (swc*nvh + swd*nvl);

        so[e & 3] = nom * fastrcp(den + EPSF) + bv;
        co[e & 3] = den * fastrcp(cden);
        if ((e & 3) == 3) {
            *(float4*)(s_out  + orow + (e - 3)) = make_float4(so[0], so[1], so[2], so[3]);
            *(float4*)(cs_out + orow + (e - 3)) = make_float4(co[0], co[1], co[2], co[3]);
        }
    }
}

extern "C" void kernel_launch(void* const* d_in, const int* in_sizes, int n_in,
                              void* d_out, int out_size, void* d_ws, size_t ws_size,
                              hipStream_t stream) {
    const float* d    = (const float*)d_in[0];
    const float* cd   = (const float*)d_in[1];
    const float* s    = (const float*)d_in[2];
    const float* cs   = (const float*)d_in[3];
    const float* wsd  = (const float*)d_in[4];
    const float* wpr  = (const float*)d_in[5];
    const float* spw  = (const float*)d_in[6];
    const float* bias = (const float*)d_in[7];

    float* out  = (float*)d_out;
    float* s_o  = out;
    float* cs_o = out + (size_t)4 * 16 * 256 * 256;

    // 64 planes x 32 tiles (8x4 of 32x64 outputs) = 2048 blocks
    fused_sndeconv<<<2048, 256, 0, stream>>>(d, cd, s, cs, wsd, wpr, spw, bias, s_o, cs_o);
}

// Round 13
// 22.267 us; speedup vs baseline: 1.3208x; 1.0703x over previous
//
#include <hip/hip_runtime.h>
#include <math.h>

#define EPSF 1e-20f
#define NEG_INF (-INFINITY)

struct TrueT  { static constexpr bool value = true;  };
struct FalseT { static constexpr bool value = false; };

__device__ __forceinline__ float softplusf(float x) {
    return fmaxf(x, 0.0f) + log1pf(expf(-fabsf(x)));
}
// fast reciprocal (v_rcp_f32) — ONLY for tolerance-protected epilogue math,
// never for argmax comparison values.
__device__ __forceinline__ float fastrcp(float x) {
    return __builtin_amdgcn_rcpf(x);
}

// Issue the 4 global loads for stage-B pair unit `unit` (pre-clamped to
// [0,1329]). Pure loads — no dependent compute, so they pipeline.
// INTERIOR: all row/col clamps fold away (tile proven in-bounds).
template<bool INTERIOR>
__device__ __forceinline__ void issue_pair_loads(
    int unit, const float* __restrict__ dp, const float* __restrict__ cdp,
    int rB, int cB,
    float& d0, float& d1, float& c0, float& c1)
{
    int wr = unit / 35;
    int t  = unit - wr * 35;
    int r  = rB + wr;
    int rl = INTERIOR ? r : (r < 0 ? 0 : (r > 255 ? 255 : r));
    int col0 = cB + 2 * t;                       // odd
    int c0i, c1i;
    if (INTERIOR) { c0i = col0; c1i = col0 + 1; }
    else {
        c0i = col0 < 0 ? 0 : (col0 > 255 ? 255 : col0);
        c1i = col0 + 1 < 0 ? 0 : (col0 + 1 > 255 ? 255 : col0 + 1);
    }
    const float* drow = dp  + rl * 256;
    const float* crow = cdp + rl * 256;
    d0 = drow[c0i];
    d1 = drow[c1i];
    c0 = crow[c0i];
    c1 = crow[c1i];
}

// One block = 32x64 output tile of one (b,c) plane. 2048 blocks x 256 threads.
// Stage B: PAIR-granularity dual argmax (38 rows x 35 col-pairs = 1330 units),
//          2-deep software-pipelined. Payload 16B: W4=(d1,c1,v2,c2), ONE
//          ds_write_b128. chain-1 value recomputed as d1*c1 downstream
//          (bit-exact); chain-2 winner's d recomputed as c2*rcp(v2) in C
//          (tolerance-protected, v2>0 guarded).
// Stage C: window = pairs (cn,cn+1) x 4 rows, kh-major/kw-ascending strict >
//          == reference flat argmax. 8 ds_read_b128 per cell (was 8+8).
// Stage D: 4-tap transposed depthwise conv + fused epilogue; lx interleaved
//          float2 -> 3 ds_read_b128 per row.
__global__ __launch_bounds__(256, 4) void fused_sndeconv(
    const float* __restrict__ d, const float* __restrict__ cd,
    const float* __restrict__ s, const float* __restrict__ cs,
    const float* __restrict__ w_s_from_d, const float* __restrict__ w_prop,
    const float* __restrict__ spatial_weight, const float* __restrict__ bias,
    float* __restrict__ s_out, float* __restrict__ cs_out)
{
    __shared__ float4 W4[38][35];        // (d1, c1, v2, c2)  20.8 KB
    __shared__ float2 lx[18][38];        // (x1, x2) interleaved; 5.3 KB
    __shared__ float  sws[16];           // total ~26.2 KB

    const int tid = threadIdx.x;
    // XCD-chunked swizzle (2048 % 8 == 0 -> bijective): vertical neighbor
    // tiles co-resident on one XCD L2.
    const int bid = blockIdx.x;
    const int blk = (bid & 7) * 256 + (bid >> 3);
    const int bc  = blk >> 5;            // plane 0..63
    const int tl  = blk & 31;
    const int by  = tl >> 2;             // 0..7  (32-row bands)
    const int bx  = tl & 3;              // 0..3  (64-col bands)
    const int c   = bc & 15;

    const int ib = by << 5;              // output row base
    const int jb = bx << 6;              // output col base
    const int mB = (ib >> 1) - 1;        // x-row base (18 rows)
    const int nB = (jb >> 1) - 1;        // x-col base (34 cols)
    const int rB = 2 * mB - 1;           // input row base (38 rows)
    const int cB = 2 * nB - 1;           // input col base (odd)

    if (tid < 16) sws[tid] = softplusf(spatial_weight[c * 16 + tid]);

    const float* dp  = d  + (size_t)bc * 65536;
    const float* cdp = cd + (size_t)bc * 65536;
    const float* sp  = s  + (size_t)bc * 16384;
    const float* csp = cs + (size_t)bc * 16384;

    const float a0 = w_s_from_d[0];
    const float a1 = w_s_from_d[1];
    const float wp = softplusf(w_prop[0]);
    const float rwp1 = fastrcp(wp + 1.0f);

    const bool interior = (by >= 1) && (by <= 6) && (bx >= 1) && (bx <= 2);

    auto runBC = [&](auto tag) {
        constexpr bool INT = decltype(tag)::value;

        // ---------- stage B: 2-deep pipelined pair argmax ----------
        float pd0[2], pd1[2], pc0[2], pc1[2];

        // prologue: unit for it=0 (tid < 256 < 1330, no clamp needed)
        issue_pair_loads<INT>(tid, dp, cdp, rB, cB, pd0[0], pd1[0], pc0[0], pc1[0]);

        #pragma unroll
        for (int it = 0; it < 6; ++it) {
            const int cur = it & 1;
            const int nxt = cur ^ 1;
            if (it < 5) {                        // compile-time after unroll
                int nu = tid + 256 * (it + 1);
                nu = nu < 1330 ? nu : 1329;      // clamp: safe redundant loads
                issue_pair_loads<INT>(nu, dp, cdp, rB, cB,
                                      pd0[nxt], pd1[nxt], pc0[nxt], pc1[nxt]);
            }
            int unit = tid + 256 * it;
            if (unit < 1330) {
                int wr = unit / 35;
                int t  = unit - wr * 35;
                bool mv0, mv1;
                if (INT) { mv0 = true; mv1 = true; }
                else {
                    int r    = rB + wr;
                    int col0 = cB + 2 * t;       // odd
                    bool rv  = (r >= 0) && (r < 256);
                    mv0 = rv && (col0 >= 0)  && (col0 <= 255);
                    mv1 = rv && (col0 >= -1) && (col0 <= 254);
                }
                float dv0 = pd0[cur], dv1 = pd1[cur];
                float cv0 = pc0[cur], cv1 = pc1[cur];

                // chain1 init (-inf,1): recomputed v1 = -inf can't win
                float b1 = NEG_INF, w1d = NEG_INF, w1c = 1.0f;
                float b2 = NEG_INF, w2c = 0.f;

                // element kw-even
                float v1 = mv0 ? dv0 * cv0          : NEG_INF;
                float v2 = mv0 ? cv0 / (dv0 + EPSF) : NEG_INF;  // EXACT div
                bool t1 = v1 > b1;
                b1 = t1 ? v1 : b1; w1d = t1 ? dv0 : w1d; w1c = t1 ? cv0 : w1c;
                bool t2 = v2 > b2;
                b2 = t2 ? v2 : b2; w2c = t2 ? cv0 : w2c;
                // element kw-odd
                v1 = mv1 ? dv1 * cv1          : NEG_INF;
                v2 = mv1 ? cv1 / (dv1 + EPSF) : NEG_INF;        // EXACT div
                t1 = v1 > b1;
                b1 = t1 ? v1 : b1; w1d = t1 ? dv1 : w1d; w1c = t1 ? cv1 : w1c;
                t2 = v2 > b2;
                b2 = t2 ? v2 : b2; w2c = t2 ? cv1 : w2c;

                W4[wr][t] = make_float4(w1d, w1c, b2, w2c);
            }
        }
        __syncthreads();

        // ---------- stage C: 2-pair x 4-row combine + prop math ----------
        #pragma unroll
        for (int it = 0; it < 3; ++it) {
            int unit = tid + 256 * it;
            if (unit < 612) {
                int cmr = unit / 34;
                int cn  = unit - cmr * 34;
                int m   = mB + cmr;
                int n   = nB + cn;
                if (!INT && (m < 0 || m > 127 || n < 0 || n > 127)) {
                    lx[cmr][cn] = make_float2(0.f, 0.f);
                } else {
                    // global loads first (overlap with LDS combine below)
                    float sv  = sp [m * 128 + n];
                    float csv = csp[m * 128 + n];

                    float b1 = NEG_INF, d1 = NEG_INF, c1 = 1.0f;
                    float b2 = NEG_INF, c2 = 0.f;
                    // kh-major, kw-ascending: row k, pair cn then cn+1
                    #pragma unroll
                    for (int k = 0; k < 4; ++k) {
                        int row = 2 * cmr + k;
                        #pragma unroll
                        for (int dt = 0; dt < 2; ++dt) {
                            float4 w4 = W4[row][cn + dt];
                            float v1 = w4.x * w4.y;          // bit-exact recompute
                            bool t1 = v1 > b1;
                            b1 = t1 ? v1 : b1; d1 = t1 ? w4.x : d1; c1 = t1 ? w4.y : c1;
                            bool t2 = w4.z > b2;
                            b2 = t2 ? w4.z : b2; c2 = t2 ? w4.w : c2;
                        }
                    }

                    // winner's d recomputed from its exact quotient:
                    // d2 ~ (d+eps)(1 +- 2^-22); if v2max==0 the whole window
                    // has cd==0 -> csfd==0 multiplies m out -> exact anyway.
                    float d2   = (b2 > 0.f) ? c2 * fastrcp(b2) : 0.f;
                    float mm_  = fabsf(d2 * fastrcp(d1 + EPSF));
                    float sfd  = (1.0f - a0 - a1) * mm_ + a0 * mm_ * mm_ + a1 * mm_ * mm_ * mm_;
                    float csfd = c1 * c2;
                    float den  = wp * csv + csfd;
                    float spv  = (wp * csv * sv + csfd * sfd) * fastrcp(den + EPSF);
                    float cp   = den * rwp1;
                    lx[cmr][cn] = make_float2(cp * spv, cp);
                }
            }
        }
    };
    if (interior) runBC(TrueT{});
    else          runBC(FalseT{});
    __syncthreads();

    // ---------------- stage D: deconv + epilogue (8 outputs/thread) ----------------
    int ii = tid >> 3, jq = tid & 7;
    int i  = ib + ii;
    int u0 = (i + 1) & 1;
    int m0 = (i + 1 - u0) >> 1;
    int pr0 = m0 - mB;                    // 1..17
    int pr1 = pr0 - 1;                    // 0..16
    float rv0 = (m0 <= 127) ? 1.f : 0.f;
    float rv1 = (m0 >= 1)   ? 1.f : 0.f;

    float wA0 = sws[u0*4 + 0], wA1 = sws[u0*4 + 1], wA2 = sws[u0*4 + 2], wA3 = sws[u0*4 + 3];
    float wC0 = sws[(u0+2)*4 + 0], wC1 = sws[(u0+2)*4 + 1], wC2 = sws[(u0+2)*4 + 2], wC3 = sws[(u0+2)*4 + 3];
    float bv  = bias[c];

    int bb = 4 * jq;                      // float2 col base (even -> 16B aligned)
    float r1a[6], r2a[6], r1b[6], r2b[6];
    {
        const float4* p = (const float4*)&lx[pr0][bb];
        float4 q0 = p[0], q1 = p[1], q2 = p[2];
        r1a[0]=q0.x; r2a[0]=q0.y; r1a[1]=q0.z; r2a[1]=q0.w;
        r1a[2]=q1.x; r2a[2]=q1.y; r1a[3]=q1.z; r2a[3]=q1.w;
        r1a[4]=q2.x; r2a[4]=q2.y; r1a[5]=q2.z; r2a[5]=q2.w;
    }
    {
        const float4* p = (const float4*)&lx[pr1][bb];
        float4 q0 = p[0], q1 = p[1], q2 = p[2];
        r1b[0]=q0.x; r2b[0]=q0.y; r1b[1]=q0.z; r2b[1]=q0.w;
        r1b[2]=q1.x; r2b[2]=q1.y; r1b[3]=q1.z; r2b[3]=q1.w;
        r1b[4]=q2.x; r2b[4]=q2.y; r1b[5]=q2.z; r2b[5]=q2.w;
    }

    int n0b = (jb >> 1) + 4 * jq;
    size_t orow = (size_t)bc * 65536 + (size_t)i * 256 + jb + 8 * jq;

    float so[4], co[4];
    #pragma unroll
    for (int e = 0; e < 8; ++e) {
        const int v0 = (e + 1) & 1;
        const int hi = 1 + ((e + 1) >> 1);
        const int lo = hi - 1;
        float swa = v0 ? wA1 : wA0;       // (u0,   v0)
        float swb = v0 ? wA3 : wA2;       // (u0,   v0+2)
        float swc = v0 ? wC1 : wC0;       // (u0+2, v0)
        float swd = v0 ? wC3 : wC2;       // (u0+2, v0+2)

        float nom = swa*r1a[hi] + swb*r1a[lo] + swc*r1b[hi] + swd*r1b[lo];
        float den = swa*r2a[hi] + swb*r2a[lo] + swc*r2b[hi] + swd*r2b[lo];

        int n0 = n0b + ((e + 1) >> 1);
        float nvh = (n0 <= 127) ? 1.f : 0.f;
        float nvl = (n0 >= 1)   ? 1.f : 0.f;
        float cden = rv0 * (swa*nvh + swb*nvl) + rv1 * (swc*nvh + swd*nvl);

        so[e & 3] = nom * fastrcp(den + EPSF) + bv;
        co[e & 3] = den * fastrcp(cden);
        if ((e & 3) == 3) {
            *(float4*)(s_out  + orow + (e - 3)) = make_float4(so[0], so[1], so[2], so[3]);
            *(float4*)(cs_out + orow + (e - 3)) = make_float4(co[0], co[1], co[2], co[3]);
        }
    }
}

extern "C" void kernel_launch(void* const* d_in, const int* in_sizes, int n_in,
                              void* d_out, int out_size, void* d_ws, size_t ws_size,
                              hipStream_t stream) {
    const float* d    = (const float*)d_in[0];
    const float* cd   = (const float*)d_in[1];
    const float* s    = (const float*)d_in[2];
    const float* cs   = (const float*)d_in[3];
    const float* wsd  = (const float*)d_in[4];
    const float* wpr  = (const float*)d_in[5];
    const float* spw  = (const float*)d_in[6];
    const float* bias = (const float*)d_in[7];

    float* out  = (float*)d_out;
    float* s_o  = out;
    float* cs_o = out + (size_t)4 * 16 * 256 * 256;

    // 64 planes x 32 tiles (8x4 of 32x64 outputs) = 2048 blocks
    fused_sndeconv<<<2048, 256, 0, stream>>>(d, cd, s, cs, wsd, wpr, spw, bias, s_o, cs_o);
}